// Round 16
// baseline (220.232 us; speedup 1.0000x reference)
//
#include <hip/hip_runtime.h>
#include <hip/hip_bf16.h>
#include <math.h>

#define T_ 8
#define N_ 2048
#define F_ 128
#define H_ 4
#define NSPT_ 32   // tiles (32 keys) per split; 2 splits x 32 x 32 = 2048 keys

typedef unsigned int u32;
typedef unsigned short ushort_t;
typedef float f32x16 __attribute__((ext_vector_type(16)));
typedef _Float16 f16x8 __attribute__((ext_vector_type(8)));
typedef u32 u32x4 __attribute__((ext_vector_type(4)));

// ---------------------------------------------------------------------------
// Kernel 1 (R11, unchanged): th = x @ W via fp16 MFMA, 2-term x split.
// ---------------------------------------------------------------------------
__global__ __launch_bounds__(256) void k_th(const float* __restrict__ x,
                                            const float* __restrict__ W,
                                            ushort_t* __restrict__ th_hi,
                                            ushort_t* __restrict__ th_hiT) {
    const int b = blockIdx.x;
    const int h = b / (T_ * (N_ / 64));
    const int rem = b % (T_ * (N_ / 64));
    const int t = rem / (N_ / 64);
    const int n0 = (rem % (N_ / 64)) * 64;
    const int tid = threadIdx.x;
    const int lane = tid & 63;
    const int w = tid >> 6;
    const int l31 = lane & 31;
    const int h5 = lane >> 5;
    const int rh = w & 1;     // row half (32 rows)
    const int gh = w >> 1;    // g half (64 cols)

    f16x8 xh[8], xl[8];
    {
        const float* xrow = x + ((size_t)t * N_ + (n0 + rh * 32 + l31)) * F_ + h5 * 8;
        #pragma unroll
        for (int ks = 0; ks < 8; ++ks) {
            float4 v0 = *reinterpret_cast<const float4*>(xrow + ks * 16);
            float4 v1 = *reinterpret_cast<const float4*>(xrow + ks * 16 + 4);
            float vv[8] = {v0.x, v0.y, v0.z, v0.w, v1.x, v1.y, v1.z, v1.w};
            f16x8 hi, lo;
            #pragma unroll
            for (int j = 0; j < 8; ++j) {
                _Float16 hh = (_Float16)vv[j];
                hi[j] = hh;
                lo[j] = (_Float16)(vv[j] - (float)hh);
            }
            xh[ks] = hi; xl[ks] = lo;
        }
    }

    f16x8 wb0[8], wb1[8];
    {
        const float* Wb = W + (size_t)h * F_ * F_ + gh * 64 + 2 * l31;
        #pragma unroll
        for (int ks = 0; ks < 8; ++ks) {
            f16x8 b0, b1;
            #pragma unroll
            for (int j = 0; j < 8; ++j) {
                float2 wv = *reinterpret_cast<const float2*>(
                    Wb + (size_t)(ks * 16 + h5 * 8 + j) * F_);
                b0[j] = (_Float16)wv.x;
                b1[j] = (_Float16)wv.y;
            }
            wb0[ks] = b0; wb1[ks] = b1;
        }
    }

    f32x16 acc0, acc1;
    #pragma unroll
    for (int r = 0; r < 16; ++r) { acc0[r] = 0.f; acc1[r] = 0.f; }
    #pragma unroll
    for (int ks = 0; ks < 8; ++ks) {
        acc0 = __builtin_amdgcn_mfma_f32_32x32x16_f16(xh[ks], wb0[ks], acc0, 0, 0, 0);
        acc1 = __builtin_amdgcn_mfma_f32_32x32x16_f16(xh[ks], wb1[ks], acc1, 0, 0, 0);
        acc0 = __builtin_amdgcn_mfma_f32_32x32x16_f16(xl[ks], wb0[ks], acc0, 0, 0, 0);
        acc1 = __builtin_amdgcn_mfma_f32_32x32x16_f16(xl[ks], wb1[ks], acc1, 0, 0, 0);
    }

    const size_t ht = (size_t)h * T_ + t;

    {
        ushort_t* base = th_hi + (ht * N_ + (size_t)(n0 + rh * 32)) * F_ + gh * 64 + 2 * l31;
        #pragma unroll
        for (int reg = 0; reg < 16; ++reg) {
            const int r = (reg & 3) + 8 * (reg >> 2) + 4 * h5;
            auto r2 = __builtin_amdgcn_cvt_pkrtz(acc0[reg], acc1[reg]);
            *reinterpret_cast<u32*>(base + (size_t)r * F_) = __builtin_bit_cast(u32, r2);
        }
    }

    {
        const int nc = (n0 >> 5) + rh;
        #pragma unroll
        for (int gs = 0; gs < 2; ++gs) {
            const int g = gh * 64 + 2 * l31 + gs;
            const f32x16& A = gs ? acc1 : acc0;
            ushort_t* bg = th_hiT + ((ht * (N_ / 32) + nc) * F_ + g) * 32;
            u32x4 run0, run1;
            run0.x = __builtin_bit_cast(u32, __builtin_amdgcn_cvt_pkrtz(A[0], A[1]));
            run0.y = __builtin_bit_cast(u32, __builtin_amdgcn_cvt_pkrtz(A[2], A[3]));
            run0.z = __builtin_bit_cast(u32, __builtin_amdgcn_cvt_pkrtz(A[4], A[5]));
            run0.w = __builtin_bit_cast(u32, __builtin_amdgcn_cvt_pkrtz(A[6], A[7]));
            run1.x = __builtin_bit_cast(u32, __builtin_amdgcn_cvt_pkrtz(A[8], A[9]));
            run1.y = __builtin_bit_cast(u32, __builtin_amdgcn_cvt_pkrtz(A[10], A[11]));
            run1.z = __builtin_bit_cast(u32, __builtin_amdgcn_cvt_pkrtz(A[12], A[13]));
            run1.w = __builtin_bit_cast(u32, __builtin_amdgcn_cvt_pkrtz(A[14], A[15]));
            *reinterpret_cast<u32x4*>(bg + 8 * h5) = run0;
            *reinterpret_cast<u32x4*>(bg + 16 + 8 * h5) = run1;
        }
    }
}

// ---------------------------------------------------------------------------
// Kernel 2 (R16): key-split x2 -> grid 1024 = 4 blocks/CU (LDS 34KB).
// 32-key tiles, single barrier per tile, double-buffered K+V (reg staging),
// T14 issue-early, base-2 softmax, deferred l-combine, pi-permuted V.
// Partials: normalized fp16 o + (m,l) f32; 2-way merge in k_out.
// ---------------------------------------------------------------------------
__global__ __launch_bounds__(256, 4) void k_attn(const ushort_t* __restrict__ th_hi,
                                                 const ushort_t* __restrict__ th_hiT,
                                                 ushort_t* __restrict__ o_norm,
                                                 float* __restrict__ ml) {
    __shared__ ushort_t kh[2][32][128];   // 16 KB
    __shared__ ushort_t vt[2][64][72];    // 18 KB

    const int tid = threadIdx.x;
    const int lane = tid & 63;
    const int w = tid >> 6;
    const int l31 = lane & 31;
    const int h5 = lane >> 5;

    // XCD-grouping swizzle: 128 vids/XCD = 4 complete (h,t) groups
    const int vid = ((blockIdx.x & 7) << 7) | (blockIdx.x >> 3);
    const int h = vid >> 8;
    const int t = (vid >> 5) & 7;
    const int qt = (vid >> 1) & 15;
    const int sp = vid & 1;
    const int q0 = qt * 128 + w * 32;
    const int tb = sp * NSPT_;            // first 32-key tile of this split
    const int pidx = ((h * 8 + t) * 16 + qt) * 2 + sp;

    const size_t ht = (size_t)h * T_ + t;
    const ushort_t* Khi_g = th_hi + ht * (N_ * F_);
    const ushort_t* VT_g  = th_hiT + ht * ((N_ / 32) * F_ * 32);
    const ushort_t* Qhi_g = th_hi + ((size_t)h * T_ + (T_ - 1)) * (N_ * F_);

    // Q fragments, pre-scaled by log2(e) (base-2 softmax)
    f16x8 qh[8];
    {
        const _Float16 L2E = (_Float16)1.4426950408889634f;
        const ushort_t* qrh = Qhi_g + (size_t)(q0 + l31) * F_ + h5 * 8;
        #pragma unroll
        for (int ks = 0; ks < 8; ++ks) {
            f16x8 qv = *reinterpret_cast<const f16x8*>(qrh + ks * 16);
            #pragma unroll
            for (int j = 0; j < 8; ++j) qv[j] *= L2E;
            qh[ks] = qv;
        }
    }

    // staging maps (256 threads)
    const int sm = tid >> 3;            // K row 0..31
    const int sfc = tid & 7;            // K 16-elem f chunk
    const int ssx = sm & 15;
    const int sg = tid >> 1;            // V g-row 0..127
    const int smh = (tid & 1) * 16;     // V m half

    f32x16 o2[4];
    #pragma unroll
    for (int gs = 0; gs < 4; ++gs)
        #pragma unroll
        for (int r = 0; r < 16; ++r) o2[gs][r] = 0.f;

    float m_run = -3e38f, l_run = 0.f;  // base-2; l per-half partial

    uint4 ka0, ka1, sv0, sv1;           // staging regs (T14)
    f16x8 pa0, pa1;                     // P fragments

    auto k_load = [&](int p) {
        const ushort_t* kp = Khi_g + (size_t)((tb + p) * 32 + sm) * F_ + sfc * 16;
        ka0 = *reinterpret_cast<const uint4*>(kp);
        ka1 = *reinterpret_cast<const uint4*>(kp + 8);
    };
    auto k_write = [&](int buf) {
        *reinterpret_cast<uint4*>(&kh[buf][sm][((sfc * 2 + 0) ^ ssx) * 8]) = ka0;
        *reinterpret_cast<uint4*>(&kh[buf][sm][((sfc * 2 + 1) ^ ssx) * 8]) = ka1;
    };
    auto v_load = [&](int p) {
        const ushort_t* vsrc = VT_g + (size_t)(tb + p) * (F_ * 32) + (size_t)sg * 32 + smh;
        sv0 = *reinterpret_cast<const uint4*>(vsrc);
        sv1 = *reinterpret_cast<const uint4*>(vsrc + 8);
    };
    auto v_write = [&](int buf) {
        ushort_t* vdst = &vt[buf][sg >> 1][(sg & 1) * 32 + smh];
        *reinterpret_cast<uint4*>(vdst) = sv0;
        *reinterpret_cast<uint4*>(vdst + 8) = sv1;
    };
    auto scores = [&](int buf) -> f32x16 {
        f32x16 S;
        #pragma unroll
        for (int r = 0; r < 16; ++r) S[r] = 0.f;
        __builtin_amdgcn_s_setprio(1);
        #pragma unroll
        for (int ks = 0; ks < 8; ++ks) {
            const f16x8 ah = *reinterpret_cast<const f16x8*>(
                &kh[buf][l31][((ks * 2 + h5) ^ (l31 & 15)) * 8]);
            S = __builtin_amdgcn_mfma_f32_32x32x16_f16(ah, qh[ks], S, 0, 0, 0);
        }
        __builtin_amdgcn_s_setprio(0);
        return S;
    };
    auto sm_only = [&](f32x16& S) {
        float m0 = fmaxf(fmaxf(S[0], S[1]), S[2]);
        float m1 = fmaxf(fmaxf(S[3], S[4]), S[5]);
        float m2 = fmaxf(fmaxf(S[6], S[7]), S[8]);
        float m3 = fmaxf(fmaxf(S[9], S[10]), S[11]);
        float m4 = fmaxf(fmaxf(S[12], S[13]), S[14]);
        float tm = fmaxf(fmaxf(fmaxf(m0, m1), m2), fmaxf(fmaxf(m3, m4), S[15]));
        tm = fmaxf(tm, __shfl_xor(tm, 32));

        if (__any(tm > m_run + 11.5416f)) {     // T13 defer (e^8 bound, base-2)
            const float Mn = fmaxf(m_run, tm);
            const float alpha = exp2f(m_run - Mn);
            l_run *= alpha;
            #pragma unroll
            for (int gs = 0; gs < 4; ++gs)
                #pragma unroll
                for (int r = 0; r < 16; ++r) o2[gs][r] *= alpha;
            m_run = Mn;
        }
        float p[16];
        #pragma unroll
        for (int r = 0; r < 16; ++r) p[r] = exp2f(S[r] - m_run);
        float ts = (((p[0] + p[1]) + (p[2] + p[3])) + ((p[4] + p[5]) + (p[6] + p[7])))
                 + (((p[8] + p[9]) + (p[10] + p[11])) + ((p[12] + p[13]) + (p[14] + p[15])));
        l_run += ts;   // per-half partial; combined once in epilogue

        u32 pk[8];
        #pragma unroll
        for (int c = 0; c < 8; ++c) {
            auto r2 = __builtin_amdgcn_cvt_pkrtz(p[2 * c], p[2 * c + 1]);
            pk[c] = __builtin_bit_cast(u32, r2);
        }
        u32x4 t0, t1;
        t0.x = pk[0]; t0.y = pk[1]; t0.z = pk[2]; t0.w = pk[3];
        t1.x = pk[4]; t1.y = pk[5]; t1.z = pk[6]; t1.w = pk[7];
        pa0 = __builtin_bit_cast(f16x8, t0);
        pa1 = __builtin_bit_cast(f16x8, t1);
    };
    auto pv_apply = [&](int buf) {
        __builtin_amdgcn_s_setprio(1);
        #pragma unroll
        for (int gs = 0; gs < 4; ++gs) {
            const int g = gs * 32 + l31;
            const ushort_t* vrow = &vt[buf][g >> 1][(g & 1) * 32];
            f16x8 v0 = *reinterpret_cast<const f16x8*>(vrow + h5 * 8);
            f16x8 v1 = *reinterpret_cast<const f16x8*>(vrow + 16 + h5 * 8);
            o2[gs] = __builtin_amdgcn_mfma_f32_32x32x16_f16(v0, pa0, o2[gs], 0, 0, 0);
            o2[gs] = __builtin_amdgcn_mfma_f32_32x32x16_f16(v1, pa1, o2[gs], 0, 0, 0);
        }
        __builtin_amdgcn_s_setprio(0);
    };

    // prologue: stage tile 0
    k_load(0); k_write(0);
    v_load(0); v_write(0);
    __syncthreads();

    for (int p = 0; p < NSPT_; ++p) {
        const bool more = (p + 1) < NSPT_;
        if (more) { k_load(p + 1); v_load(p + 1); }   // issue-early (T14)
        f32x16 S = scores(p & 1);
        if (more) { k_write((p + 1) & 1); v_write((p + 1) & 1); }
        sm_only(S);
        pv_apply(p & 1);
        __syncthreads();
    }

    // epilogue: combine l halves, write normalized fp16 partial + (m, l_tot)
    const float l_tot = l_run + __shfl_xor(l_run, 32);
    const float inv = 1.f / l_tot;
    const int qin = w * 32 + l31;
    ushort_t* ob = o_norm + (size_t)pidx * (128 * 128) + (size_t)qin * 128;
    #pragma unroll
    for (int gs = 0; gs < 4; ++gs)
        #pragma unroll
        for (int rp = 0; rp < 8; ++rp) {
            const int r = rp * 2;
            const int g = gs * 32 + (r & 3) + 8 * (r >> 2) + 4 * h5;  // even
            auto r2 = __builtin_amdgcn_cvt_pkrtz(o2[gs][r] * inv, o2[gs][r + 1] * inv);
            *reinterpret_cast<u32*>(ob + g) = __builtin_bit_cast(u32, r2);
        }
    if (h5 == 0) {
        ml[(size_t)pidx * 256 + qin] = m_run;
        ml[(size_t)pidx * 256 + 128 + qin] = l_tot;
    }
}

// ---------------------------------------------------------------------------
// Kernel 3 (R16): 2-way flash merge + t-sum + elu + head-mean. fp16 partials.
// thread = (n, g-quad): 65536 threads = 256 blocks x 256.
// ---------------------------------------------------------------------------
__global__ __launch_bounds__(256) void k_out(const ushort_t* __restrict__ o_norm,
                                             const float* __restrict__ ml,
                                             float* __restrict__ out) {
    const int idx = blockIdx.x * blockDim.x + threadIdx.x;
    const int n = idx >> 5;
    const int g0 = (idx & 31) * 4;
    const int qt = n >> 7;
    const int qin = n & 127;
    const float invT = 1.f / (float)T_;

    float acc[4] = {0.f, 0.f, 0.f, 0.f};
    #pragma unroll
    for (int h = 0; h < H_; ++h) {
        float hs[4] = {0.f, 0.f, 0.f, 0.f};
        #pragma unroll
        for (int t = 0; t < T_; ++t) {
            const size_t base2 = (size_t)((h * 8 + t) * 16 + qt) * 2;
            const float m0 = ml[(base2 + 0) * 256 + qin];
            const float l0 = ml[(base2 + 0) * 256 + 128 + qin];
            const float m1 = ml[(base2 + 1) * 256 + qin];
            const float l1 = ml[(base2 + 1) * 256 + 128 + qin];
            const float M = fmaxf(m0, m1);
            const float w0 = l0 * exp2f(m0 - M);
            const float w1 = l1 * exp2f(m1 - M);
            const float invW = 1.f / (w0 + w1);
            const float c0 = w0 * invW, c1 = w1 * invW;
            #pragma unroll
            for (int s = 0; s < 2; ++s) {
                const float cs = s ? c1 : c0;
                uint2 od = *reinterpret_cast<const uint2*>(
                    o_norm + (base2 + s) * (128 * 128) + (size_t)qin * 128 + g0);
                hs[0] += cs * (float)__builtin_bit_cast(_Float16, (ushort_t)(od.x & 0xffff));
                hs[1] += cs * (float)__builtin_bit_cast(_Float16, (ushort_t)(od.x >> 16));
                hs[2] += cs * (float)__builtin_bit_cast(_Float16, (ushort_t)(od.y & 0xffff));
                hs[3] += cs * (float)__builtin_bit_cast(_Float16, (ushort_t)(od.y >> 16));
            }
        }
        #pragma unroll
        for (int k = 0; k < 4; ++k) {
            const float e = hs[k] * invT;
            acc[k] += (e > 0.f) ? e : (expf(e) - 1.f);
        }
    }
    float4 r = {acc[0] * 0.25f, acc[1] * 0.25f, acc[2] * 0.25f, acc[3] * 0.25f};
    *reinterpret_cast<float4*>(out + (size_t)n * F_ + g0) = r;
}

extern "C" void kernel_launch(void* const* d_in, const int* in_sizes, int n_in,
                              void* d_out, int out_size, void* d_ws, size_t ws_size,
                              hipStream_t stream) {
    const float* x = (const float*)d_in[0];   // (T, N, F)
    const float* W = (const float*)d_in[1];   // (H, F, F)
    float* out = (float*)d_out;               // (N, F)

    // ws: th_hi 16MB | th_hiT 16MB | o_norm(fp16) 32MB | ml 1MB  (65MB)
    const size_t TH = (size_t)H_ * T_ * N_ * F_;        // 8,388,608
    const size_t NPART = (size_t)H_ * T_ * 16 * 2;      // 1024 partials
    ushort_t* th_hi  = (ushort_t*)d_ws;
    ushort_t* th_hiT = th_hi + TH;
    ushort_t* o_norm = th_hiT + TH;
    float* ml = (float*)(o_norm + NPART * 128 * 128);

    k_th<<<H_ * T_ * (N_ / 64), 256, 0, stream>>>(x, W, th_hi, th_hiT);
    k_attn<<<1024, 256, 0, stream>>>(th_hi, th_hiT, o_norm, ml);
    k_out<<<(N_ * 32) / 256, 256, 0, stream>>>(o_norm, ml, out);
}

// Round 17
// 116.713 us; speedup vs baseline: 1.8870x; 1.8870x over previous
//
#include <hip/hip_runtime.h>
#include <hip/hip_bf16.h>
#include <math.h>

#define T_ 8
#define N_ 2048
#define F_ 128
#define H_ 4
#define NT2_ (N_ / 64)   // 32 key tiles (64 keys each) per (h,t)

typedef unsigned int u32;
typedef unsigned short ushort_t;
typedef float f32x16 __attribute__((ext_vector_type(16)));
typedef _Float16 f16x8 __attribute__((ext_vector_type(8)));
typedef u32 u32x4 __attribute__((ext_vector_type(4)));

// ---------------------------------------------------------------------------
// Kernel 1 (R11): th = x @ W via fp16 MFMA, 2-term x split.
// ---------------------------------------------------------------------------
__global__ __launch_bounds__(256) void k_th(const float* __restrict__ x,
                                            const float* __restrict__ W,
                                            ushort_t* __restrict__ th_hi,
                                            ushort_t* __restrict__ th_hiT) {
    const int b = blockIdx.x;
    const int h = b / (T_ * (N_ / 64));
    const int rem = b % (T_ * (N_ / 64));
    const int t = rem / (N_ / 64);
    const int n0 = (rem % (N_ / 64)) * 64;
    const int tid = threadIdx.x;
    const int lane = tid & 63;
    const int w = tid >> 6;
    const int l31 = lane & 31;
    const int h5 = lane >> 5;
    const int rh = w & 1;     // row half (32 rows)
    const int gh = w >> 1;    // g half (64 cols)

    f16x8 xh[8], xl[8];
    {
        const float* xrow = x + ((size_t)t * N_ + (n0 + rh * 32 + l31)) * F_ + h5 * 8;
        #pragma unroll
        for (int ks = 0; ks < 8; ++ks) {
            float4 v0 = *reinterpret_cast<const float4*>(xrow + ks * 16);
            float4 v1 = *reinterpret_cast<const float4*>(xrow + ks * 16 + 4);
            float vv[8] = {v0.x, v0.y, v0.z, v0.w, v1.x, v1.y, v1.z, v1.w};
            f16x8 hi, lo;
            #pragma unroll
            for (int j = 0; j < 8; ++j) {
                _Float16 hh = (_Float16)vv[j];
                hi[j] = hh;
                lo[j] = (_Float16)(vv[j] - (float)hh);
            }
            xh[ks] = hi; xl[ks] = lo;
        }
    }

    f16x8 wb0[8], wb1[8];
    {
        const float* Wb = W + (size_t)h * F_ * F_ + gh * 64 + 2 * l31;
        #pragma unroll
        for (int ks = 0; ks < 8; ++ks) {
            f16x8 b0, b1;
            #pragma unroll
            for (int j = 0; j < 8; ++j) {
                float2 wv = *reinterpret_cast<const float2*>(
                    Wb + (size_t)(ks * 16 + h5 * 8 + j) * F_);
                b0[j] = (_Float16)wv.x;
                b1[j] = (_Float16)wv.y;
            }
            wb0[ks] = b0; wb1[ks] = b1;
        }
    }

    f32x16 acc0, acc1;
    #pragma unroll
    for (int r = 0; r < 16; ++r) { acc0[r] = 0.f; acc1[r] = 0.f; }
    #pragma unroll
    for (int ks = 0; ks < 8; ++ks) {
        acc0 = __builtin_amdgcn_mfma_f32_32x32x16_f16(xh[ks], wb0[ks], acc0, 0, 0, 0);
        acc1 = __builtin_amdgcn_mfma_f32_32x32x16_f16(xh[ks], wb1[ks], acc1, 0, 0, 0);
        acc0 = __builtin_amdgcn_mfma_f32_32x32x16_f16(xl[ks], wb0[ks], acc0, 0, 0, 0);
        acc1 = __builtin_amdgcn_mfma_f32_32x32x16_f16(xl[ks], wb1[ks], acc1, 0, 0, 0);
    }

    const size_t ht = (size_t)h * T_ + t;

    {
        ushort_t* base = th_hi + (ht * N_ + (size_t)(n0 + rh * 32)) * F_ + gh * 64 + 2 * l31;
        #pragma unroll
        for (int reg = 0; reg < 16; ++reg) {
            const int r = (reg & 3) + 8 * (reg >> 2) + 4 * h5;
            auto r2 = __builtin_amdgcn_cvt_pkrtz(acc0[reg], acc1[reg]);
            *reinterpret_cast<u32*>(base + (size_t)r * F_) = __builtin_bit_cast(u32, r2);
        }
    }

    {
        const int nc = (n0 >> 5) + rh;
        #pragma unroll
        for (int gs = 0; gs < 2; ++gs) {
            const int g = gh * 64 + 2 * l31 + gs;
            const f32x16& A = gs ? acc1 : acc0;
            ushort_t* bg = th_hiT + ((ht * (N_ / 32) + nc) * F_ + g) * 32;
            u32x4 run0, run1;
            run0.x = __builtin_bit_cast(u32, __builtin_amdgcn_cvt_pkrtz(A[0], A[1]));
            run0.y = __builtin_bit_cast(u32, __builtin_amdgcn_cvt_pkrtz(A[2], A[3]));
            run0.z = __builtin_bit_cast(u32, __builtin_amdgcn_cvt_pkrtz(A[4], A[5]));
            run0.w = __builtin_bit_cast(u32, __builtin_amdgcn_cvt_pkrtz(A[6], A[7]));
            run1.x = __builtin_bit_cast(u32, __builtin_amdgcn_cvt_pkrtz(A[8], A[9]));
            run1.y = __builtin_bit_cast(u32, __builtin_amdgcn_cvt_pkrtz(A[10], A[11]));
            run1.z = __builtin_bit_cast(u32, __builtin_amdgcn_cvt_pkrtz(A[12], A[13]));
            run1.w = __builtin_bit_cast(u32, __builtin_amdgcn_cvt_pkrtz(A[14], A[15]));
            *reinterpret_cast<u32x4*>(bg + 8 * h5) = run0;
            *reinterpret_cast<u32x4*>(bg + 16 + 8 * h5) = run1;
        }
    }
}

// ---------------------------------------------------------------------------
// Kernel 2 (R14, proven 102.6us): 64-key tiles, one barrier per tile (32),
// dual score chains, merged 32-wide softmax, 16 PV MFMA, reg staging,
// 2-deep buffers, same-iter PV. kh[2][64][128]+vt[2][128][72]=68KB, 2 blk/CU.
// ---------------------------------------------------------------------------
__global__ __launch_bounds__(256, 2) void k_attn(const ushort_t* __restrict__ th_hi,
                                                 const ushort_t* __restrict__ th_hiT,
                                                 ushort_t* __restrict__ s_part) {
    __shared__ ushort_t kh[2][64][128];
    __shared__ ushort_t vt[2][128][72];

    const int tid = threadIdx.x;
    const int lane = tid & 63;
    const int w = tid >> 6;
    const int l31 = lane & 31;
    const int h5 = lane >> 5;

    // XCD-grouping swizzle (proven: FETCH ~17MB): 64 vids per XCD
    const int vid = ((blockIdx.x & 7) << 6) | (blockIdx.x >> 3);
    const int h = vid >> 7;
    const int t = (vid >> 4) & 7;
    const int qt = vid & 15;
    const int q0 = qt * 128 + w * 32;

    const size_t ht = (size_t)h * T_ + t;
    const ushort_t* Khi_g = th_hi + ht * (N_ * F_);
    const ushort_t* VT_g  = th_hiT + ht * ((N_ / 32) * F_ * 32);
    const ushort_t* Qhi_g = th_hi + ((size_t)h * T_ + (T_ - 1)) * (N_ * F_);

    // Q fragments, pre-scaled by log2(e) (base-2 softmax)
    f16x8 qh[8];
    {
        const _Float16 L2E = (_Float16)1.4426950408889634f;
        const ushort_t* qrh = Qhi_g + (size_t)(q0 + l31) * F_ + h5 * 8;
        #pragma unroll
        for (int ks = 0; ks < 8; ++ks) {
            f16x8 qv = *reinterpret_cast<const f16x8*>(qrh + ks * 16);
            #pragma unroll
            for (int j = 0; j < 8; ++j) qv[j] *= L2E;
            qh[ks] = qv;
        }
    }

    // staging maps
    const int sm = tid >> 2;            // K row 0..63
    const int sfc = tid & 3;            // K 64B quarter (4 uint4)
    const int ssx = sm & 15;
    const int sg = tid >> 1;            // V g-row 0..127
    const int smh = (tid & 1) * 16;     // V m half (16 ushorts)

    f32x16 o2[4];
    #pragma unroll
    for (int gs = 0; gs < 4; ++gs)
        #pragma unroll
        for (int r = 0; r < 16; ++r) o2[gs][r] = 0.f;

    float m_run = -3e38f, l_run = 0.f;  // base-2 units; l per-half partial

    uint4 ka0, ka1, ka2, ka3;           // K staging regs (64B/thread)
    uint4 sv0, sv1, sv2, sv3;           // V staging regs (2 chunks)
    f16x8 pa0, pa1, pa2, pa3;           // P fragments (keys 0..31 / 32..63)

    auto k_load = [&](int mt) {
        const ushort_t* kp = Khi_g + (size_t)(mt * 64 + sm) * F_ + sfc * 32;
        ka0 = *reinterpret_cast<const uint4*>(kp);
        ka1 = *reinterpret_cast<const uint4*>(kp + 8);
        ka2 = *reinterpret_cast<const uint4*>(kp + 16);
        ka3 = *reinterpret_cast<const uint4*>(kp + 24);
    };
    auto k_write = [&](int buf) {
        *reinterpret_cast<uint4*>(&kh[buf][sm][((sfc * 4 + 0) ^ ssx) * 8]) = ka0;
        *reinterpret_cast<uint4*>(&kh[buf][sm][((sfc * 4 + 1) ^ ssx) * 8]) = ka1;
        *reinterpret_cast<uint4*>(&kh[buf][sm][((sfc * 4 + 2) ^ ssx) * 8]) = ka2;
        *reinterpret_cast<uint4*>(&kh[buf][sm][((sfc * 4 + 3) ^ ssx) * 8]) = ka3;
    };
    auto v_load = [&](int mt) {
        const ushort_t* v0 = VT_g + (size_t)(2 * mt) * (F_ * 32) + (size_t)sg * 32 + smh;
        const ushort_t* v1 = VT_g + (size_t)(2 * mt + 1) * (F_ * 32) + (size_t)sg * 32 + smh;
        sv0 = *reinterpret_cast<const uint4*>(v0);
        sv1 = *reinterpret_cast<const uint4*>(v0 + 8);
        sv2 = *reinterpret_cast<const uint4*>(v1);
        sv3 = *reinterpret_cast<const uint4*>(v1 + 8);
    };
    auto v_write = [&](int buf) {
        ushort_t* d0 = &vt[buf][sg >> 1][(sg & 1) * 32 + smh];
        ushort_t* d1 = &vt[buf][64 + (sg >> 1)][(sg & 1) * 32 + smh];
        *reinterpret_cast<uint4*>(d0) = sv0;
        *reinterpret_cast<uint4*>(d0 + 8) = sv1;
        *reinterpret_cast<uint4*>(d1) = sv2;
        *reinterpret_cast<uint4*>(d1 + 8) = sv3;
    };
    auto scores = [&](int buf, f32x16& S0, f32x16& S1) {
        #pragma unroll
        for (int r = 0; r < 16; ++r) { S0[r] = 0.f; S1[r] = 0.f; }
        __builtin_amdgcn_s_setprio(1);
        #pragma unroll
        for (int ks = 0; ks < 8; ++ks) {
            const int xo = ((ks * 2 + h5) ^ (l31 & 15)) * 8;
            const f16x8 a0 = *reinterpret_cast<const f16x8*>(&kh[buf][l31][xo]);
            const f16x8 a1 = *reinterpret_cast<const f16x8*>(&kh[buf][32 + l31][xo]);
            S0 = __builtin_amdgcn_mfma_f32_32x32x16_f16(a0, qh[ks], S0, 0, 0, 0);
            S1 = __builtin_amdgcn_mfma_f32_32x32x16_f16(a1, qh[ks], S1, 0, 0, 0);
        }
        __builtin_amdgcn_s_setprio(0);
    };
    // merged softmax over 64 keys (32 values per lane-half)
    auto sm2 = [&](f32x16& S0, f32x16& S1) {
        float cm[8];
        #pragma unroll
        for (int r = 0; r < 8; ++r)
            cm[r] = fmaxf(fmaxf(S0[2 * r], S1[2 * r]), fmaxf(S0[2 * r + 1], S1[2 * r + 1]));
        float t0 = fmaxf(fmaxf(cm[0], cm[1]), cm[2]);
        float t1 = fmaxf(fmaxf(cm[3], cm[4]), cm[5]);
        float tm = fmaxf(fmaxf(cm[6], cm[7]), fmaxf(t0, t1));
        tm = fmaxf(tm, __shfl_xor(tm, 32));

        if (__any(tm > m_run + 11.5416f)) {     // T13 defer (e^8 bound, base-2)
            const float Mn = fmaxf(m_run, tm);
            const float alpha = exp2f(m_run - Mn);
            l_run *= alpha;
            #pragma unroll
            for (int gs = 0; gs < 4; ++gs)
                #pragma unroll
                for (int r = 0; r < 16; ++r) o2[gs][r] *= alpha;
            m_run = Mn;
        }
        float p0[16], p1[16];
        #pragma unroll
        for (int r = 0; r < 16; ++r) {
            p0[r] = exp2f(S0[r] - m_run);
            p1[r] = exp2f(S1[r] - m_run);
        }
        float ts = 0.f;
        #pragma unroll
        for (int r = 0; r < 16; ++r) ts += p0[r] + p1[r];
        l_run += ts;   // per-half partial; combined once in epilogue

        u32 pk[16];
        #pragma unroll
        for (int c = 0; c < 8; ++c) {
            auto r2 = __builtin_amdgcn_cvt_pkrtz(p0[2 * c], p0[2 * c + 1]);
            pk[c] = __builtin_bit_cast(u32, r2);
            auto r3 = __builtin_amdgcn_cvt_pkrtz(p1[2 * c], p1[2 * c + 1]);
            pk[8 + c] = __builtin_bit_cast(u32, r3);
        }
        u32x4 t0v, t1v, t2v, t3v;
        t0v.x = pk[0]; t0v.y = pk[1]; t0v.z = pk[2]; t0v.w = pk[3];
        t1v.x = pk[4]; t1v.y = pk[5]; t1v.z = pk[6]; t1v.w = pk[7];
        t2v.x = pk[8]; t2v.y = pk[9]; t2v.z = pk[10]; t2v.w = pk[11];
        t3v.x = pk[12]; t3v.y = pk[13]; t3v.z = pk[14]; t3v.w = pk[15];
        pa0 = __builtin_bit_cast(f16x8, t0v);
        pa1 = __builtin_bit_cast(f16x8, t1v);
        pa2 = __builtin_bit_cast(f16x8, t2v);
        pa3 = __builtin_bit_cast(f16x8, t3v);
    };
    auto pv_apply = [&](int buf) {
        __builtin_amdgcn_s_setprio(1);
        #pragma unroll
        for (int gs = 0; gs < 4; ++gs) {
            const int g = gs * 32 + l31;
            const ushort_t* vr0 = &vt[buf][g >> 1][(g & 1) * 32];
            const ushort_t* vr1 = &vt[buf][64 + (g >> 1)][(g & 1) * 32];
            f16x8 v0 = *reinterpret_cast<const f16x8*>(vr0 + h5 * 8);
            f16x8 v1 = *reinterpret_cast<const f16x8*>(vr0 + 16 + h5 * 8);
            f16x8 v2 = *reinterpret_cast<const f16x8*>(vr1 + h5 * 8);
            f16x8 v3 = *reinterpret_cast<const f16x8*>(vr1 + 16 + h5 * 8);
            o2[gs] = __builtin_amdgcn_mfma_f32_32x32x16_f16(v0, pa0, o2[gs], 0, 0, 0);
            o2[gs] = __builtin_amdgcn_mfma_f32_32x32x16_f16(v1, pa1, o2[gs], 0, 0, 0);
            o2[gs] = __builtin_amdgcn_mfma_f32_32x32x16_f16(v2, pa2, o2[gs], 0, 0, 0);
            o2[gs] = __builtin_amdgcn_mfma_f32_32x32x16_f16(v3, pa3, o2[gs], 0, 0, 0);
        }
        __builtin_amdgcn_s_setprio(0);
    };

    // prologue: stage tile 0
    k_load(0); k_write(0);
    v_load(0); v_write(0);
    __syncthreads();

    for (int p = 0; p < NT2_; ++p) {
        const bool more = (p + 1) < NT2_;
        if (more) { k_load(p + 1); v_load(p + 1); }   // issue-early (T14)
        f32x16 S0, S1;
        scores(p & 1, S0, S1);
        if (more) { k_write((p + 1) & 1); v_write((p + 1) & 1); }
        sm2(S0, S1);
        pv_apply(p & 1);
        __syncthreads();
    }

    // epilogue: combine l halves, normalize, pack fp16, scatter-store out^T
    const float l_tot = l_run + __shfl_xor(l_run, 32);
    const float inv = 1.f / l_tot;
    ushort_t* dst = s_part + (ht * N_ + (size_t)(q0 + l31)) * F_;
    #pragma unroll
    for (int gs = 0; gs < 4; ++gs)
        #pragma unroll
        for (int rp = 0; rp < 8; ++rp) {
            const int r = rp * 2;
            const int g = gs * 32 + (r & 3) + 8 * (r >> 2) + 4 * h5;  // even
            auto r2 = __builtin_amdgcn_cvt_pkrtz(o2[gs][r] * inv, o2[gs][r + 1] * inv);
            *reinterpret_cast<u32*>(dst + g) = __builtin_bit_cast(u32, r2);
        }
}

// ---------------------------------------------------------------------------
// Kernel 3: out[n,g] = mean_h elu( (1/T) * sum_t s_part[h][t][n][g] ), fp16 in
// ---------------------------------------------------------------------------
__global__ __launch_bounds__(256) void k_out(const ushort_t* __restrict__ s_part,
                                             float* __restrict__ out) {
    const int idx = blockIdx.x * blockDim.x + threadIdx.x;
    if (idx >= (N_ * F_) / 4) return;
    const int n = idx >> 5;
    const int g0 = (idx & 31) * 4;
    const float invT = 1.f / (float)T_;

    float acc[4] = {0.f, 0.f, 0.f, 0.f};
    #pragma unroll
    for (int h = 0; h < H_; ++h) {
        float hs[4] = {0.f, 0.f, 0.f, 0.f};
        #pragma unroll
        for (int t = 0; t < T_; ++t) {
            const ushort_t* p = s_part + ((size_t)(h * T_ + t) * N_ + n) * F_ + g0;
            uint2 od = *reinterpret_cast<const uint2*>(p);
            hs[0] += (float)__builtin_bit_cast(_Float16, (ushort_t)(od.x & 0xffff));
            hs[1] += (float)__builtin_bit_cast(_Float16, (ushort_t)(od.x >> 16));
            hs[2] += (float)__builtin_bit_cast(_Float16, (ushort_t)(od.y & 0xffff));
            hs[3] += (float)__builtin_bit_cast(_Float16, (ushort_t)(od.y >> 16));
        }
        #pragma unroll
        for (int k = 0; k < 4; ++k) {
            const float e = hs[k] * invT;
            acc[k] += (e > 0.f) ? e : (expf(e) - 1.f);
        }
    }
    float4 r = {acc[0] * 0.25f, acc[1] * 0.25f, acc[2] * 0.25f, acc[3] * 0.25f};
    *reinterpret_cast<float4*>(out + (size_t)n * F_ + g0) = r;
}

extern "C" void kernel_launch(void* const* d_in, const int* in_sizes, int n_in,
                              void* d_out, int out_size, void* d_ws, size_t ws_size,
                              hipStream_t stream) {
    const float* x = (const float*)d_in[0];   // (T, N, F)
    const float* W = (const float*)d_in[1];   // (H, F, F)
    float* out = (float*)d_out;               // (N, F)

    // ws layout: th_hi 16MB | th_hiT 16MB | s_part(fp16) 16MB  (48MB)
    const size_t TH = (size_t)H_ * T_ * N_ * F_;        // 8,388,608
    ushort_t* th_hi  = (ushort_t*)d_ws;
    ushort_t* th_hiT = th_hi + TH;
    ushort_t* s_part = th_hiT + TH;

    k_th<<<H_ * T_ * (N_ / 64), 256, 0, stream>>>(x, W, th_hi, th_hiT);
    k_attn<<<512, 256, 0, stream>>>(th_hi, th_hiT, s_part);
    k_out<<<(N_ * F_ / 4 + 255) / 256, 256, 0, stream>>>(s_part, out);
}